// Round 4
// baseline (1733.099 us; speedup 1.0000x reference)
//
#include <hip/hip_runtime.h>
#include <cstdint>

typedef unsigned uint;
typedef unsigned short u16;
typedef int v4i  __attribute__((ext_vector_type(4)));
typedef int v16i __attribute__((ext_vector_type(16)));

// d_ws word layout:
//   [0,144)       w1 signs as +-1.0f
//   [144,1424)    W2B: conv2 B-frags, frag f=s*64+l, 4 words each (16 i8)
//   [1424,3728)   W3B: conv3 B-frags, frag f=s*64+l, 4 words each
//   [3728,8568)   wfc packed+expanded to 22x22 grid (10*484 words)
static constexpr int WS_W2B = 144;
static constexpr int WS_W3B = 1424;
static constexpr int WS_FC  = 3728;

// LDS byte offsets (all phases disjoint, barriers between)
static constexpr int L_XS  = 0;      // float[784]   (conv1 in)
static constexpr int L_W1  = 3136;   // float[144]   (conv1 weights)
static constexpr int L_H1B = 3712;   // u16[676]     (conv1 out / conv2 in, bit ic)
static constexpr int L_H2B = 5064;   // uint[576]    (conv2 out / conv3 in, bit ic)
static constexpr int L_H3  = 7368;   // uint[484]    (conv3 out / FC in, bit ic)
static constexpr int L_RED = 9304;   // uint[4][5]
static constexpr int L_LG  = 9384;   // float[10]
static constexpr int L_TOT = 9424;

__global__ __launch_bounds__(256) void pack_kernel(
    const float* __restrict__ w1, const float* __restrict__ w2,
    const float* __restrict__ w3, const float* __restrict__ wfc,
    uint* __restrict__ wsu)
{
    int gid = blockIdx.x * 256 + threadIdx.x;
    if (gid < 144) {
        ((float*)wsu)[gid] = (w1[gid] >= 0.f) ? 1.f : -1.f;
    } else if (gid < 464) {
        // conv2 B fragment: oc = l&31, tap = 2s + (l>>5), ic = e (K = tap*16+ic)
        int f = gid - 144, s = f >> 6, l = f & 63;
        int oc = l & 31, tap = s * 2 + (l >> 5);
        uint w[4] = {0u, 0u, 0u, 0u};
        if (tap < 9) {
            for (int e = 0; e < 16; ++e) {
                uint b = (w2[(oc * 16 + e) * 9 + tap] >= 0.f) ? 0x01u : 0xFFu;
                w[e >> 2] |= b << (8 * (e & 3));
            }
        }
        for (int j = 0; j < 4; ++j) wsu[WS_W2B + f * 4 + j] = w[j];
    } else if (gid < 1040) {
        // conv3 B fragment: oc = l&31, tap = s, ic = (l>>5)*16 + e (K = tap*32+ic)
        int f = gid - 464, s = f >> 6, l = f & 63;
        int oc = l & 31, icb = (l >> 5) * 16;
        uint w[4] = {0u, 0u, 0u, 0u};
        for (int e = 0; e < 16; ++e) {
            uint b = (w3[(oc * 32 + icb + e) * 9 + s] >= 0.f) ? 0x01u : 0xFFu;
            w[e >> 2] |= b << (8 * (e & 3));
        }
        for (int j = 0; j < 4; ++j) wsu[WS_W3B + f * 4 + j] = w[j];
    } else if (gid < 5880) {
        int f = gid - 1040, o = f / 484, p = f % 484;
        int Y = p / 22, X = p % 22;
        const float* base = wfc + o * 3872 + (Y >> 1) * 11 + (X >> 1);
        uint bits = 0;
        for (int c = 0; c < 32; ++c)
            bits |= (base[c * 121] >= 0.f ? 1u : 0u) << c;
        wsu[WS_FC + f] = bits;
    }
}

// 4 sign bits -> 4 i8 bytes (+1 / -1)
__device__ __forceinline__ int expand4(uint t) {
    return (int)~(((t * 0x00204081u) & 0x01010101u) * 0xFEu);
}

__global__ __launch_bounds__(256, 7) void binet_kernel(
    const float* __restrict__ x, const uint* __restrict__ wsu,
    const float* __restrict__ bfc, float* __restrict__ out)
{
    __shared__ __align__(16) unsigned char lds[L_TOT];
    const int t = threadIdx.x;
    const int img = blockIdx.x;
    const int l = t & 63, wave = t >> 6, half = l >> 5;

    float* xs  = (float*)(lds + L_XS);
    float* w1f = (float*)(lds + L_W1);
    u16*   h1b = (u16*)(lds + L_H1B);
    uint*  h2b = (uint*)(lds + L_H2B);
    uint*  h3  = (uint*)(lds + L_H3);
    uint (*red)[5] = (uint(*)[5])(lds + L_RED);
    float* lg  = (float*)(lds + L_LG);

    // ---- load image + conv1 weights into LDS ----
    {
        const float* xin = x + (size_t)img * 784;
        for (int i = t; i < 784; i += 256) xs[i] = xin[i];
        if (t < 144) w1f[t] = ((const float*)wsu)[t];
    }
    __syncthreads();

    // ---- conv1: fp32 fast path, rare fp64 fallback; pack 16 sign bits ----
    {
        const int p0 = t, p1 = t + 256, p2 = t + 512;
        const bool has2 = (p2 < 676);
        const int y0 = p0 / 26, x0 = p0 % 26;
        const int y1 = p1 / 26, x1 = p1 % 26;
        const int y2 = has2 ? p2 / 26 : 0, x2 = has2 ? p2 % 26 : 0;
        float xv0[9], xv1[9], xv2[9];
        #pragma unroll
        for (int ky = 0; ky < 3; ++ky)
            #pragma unroll
            for (int kx = 0; kx < 3; ++kx) {
                xv0[ky*3+kx] = xs[(y0+ky)*28 + x0 + kx];
                xv1[ky*3+kx] = xs[(y1+ky)*28 + x1 + kx];
                xv2[ky*3+kx] = xs[(y2+ky)*28 + x2 + kx];
            }
        uint m0 = 0, m1 = 0, m2 = 0;
        for (int oc = 0; oc < 16; ++oc) {
            float s0 = 0.f, s1 = 0.f, s2 = 0.f;
            #pragma unroll
            for (int k = 0; k < 9; ++k) {
                float w = w1f[oc*9 + k];          // uniform -> LDS broadcast
                s0 = fmaf(xv0[k], w, s0);
                s1 = fmaf(xv1[k], w, s1);
                s2 = fmaf(xv2[k], w, s2);
            }
            bool b0 = (s0 >= 0.f), b1 = (s1 >= 0.f), b2 = (s2 >= 0.f);
            // fp32 worst-case accum error ~2.5e-5 << 1e-4: outside the band
            // the fp32 sign equals the exact (fp64) sign.
            if (__builtin_expect(fabsf(s0) < 1e-4f, 0)) {
                double sd = 0.0;
                for (int k = 0; k < 9; ++k) sd += (double)xv0[k] * (double)w1f[oc*9+k];
                b0 = (sd >= 0.0);
            }
            if (__builtin_expect(fabsf(s1) < 1e-4f, 0)) {
                double sd = 0.0;
                for (int k = 0; k < 9; ++k) sd += (double)xv1[k] * (double)w1f[oc*9+k];
                b1 = (sd >= 0.0);
            }
            if (__builtin_expect(fabsf(s2) < 1e-4f, 0)) {
                double sd = 0.0;
                for (int k = 0; k < 9; ++k) sd += (double)xv2[k] * (double)w1f[oc*9+k];
                b2 = (sd >= 0.0);
            }
            m0 |= (uint)b0 << oc;
            m1 |= (uint)b1 << oc;
            m2 |= (uint)b2 << oc;
        }
        h1b[p0] = (u16)m0;
        h1b[p1] = (u16)m1;
        if (has2) h1b[p2] = (u16)m2;
    }
    __syncthreads();

    // ---- conv2 via i8 MFMA: M=576 pos, N=32 oc, K=144 (pad 160) ----
    {
        const v4i* w2bp = (const v4i*)(wsu + WS_W2B);
        v4i b2f[5];
        #pragma unroll
        for (int s = 0; s < 5; ++s) b2f[s] = w2bp[s*64 + l];
        for (int tile = wave; tile < 18; tile += 4) {
            const int mb = tile * 32;
            const int row = mb + (l & 31);
            const int y = row / 24, xx = row % 24;
            v16i acc = {0,0,0,0,0,0,0,0,0,0,0,0,0,0,0,0};
            #pragma unroll
            for (int s = 0; s < 5; ++s) {
                int tap = s*2 + half; if (tap > 8) tap = 8;  // B zero-padded for tap 9
                int ky = tap / 3, kx = tap - ky*3;
                uint bits = (uint)h1b[(y + ky)*26 + (xx + kx)];
                v4i a;
                a[0] = expand4(bits & 0xFu);
                a[1] = expand4((bits >> 4) & 0xFu);
                a[2] = expand4((bits >> 8) & 0xFu);
                a[3] = expand4((bits >> 12) & 0xFu);
                acc = __builtin_amdgcn_mfma_i32_32x32x32_i8(a, b2f[s], acc, 0, 0, 0);
            }
            #pragma unroll
            for (int r = 0; r < 16; ++r) {
                unsigned long long mm = __ballot(acc[r] >= 0);  // bit l = sign of oc l
                int ra = mb + (r & 3) + 8*(r >> 2);
                if (l < 2) {
                    uint val = (l == 0) ? (uint)mm : (uint)(mm >> 32);
                    h2b[ra + 4*l] = val;
                }
            }
        }
    }
    __syncthreads();

    // ---- conv3 via i8 MFMA: M=484 (pad 512), N=32 oc, K=288 ----
    {
        const v4i* w3bp = (const v4i*)(wsu + WS_W3B);
        v4i b3f[9];
        #pragma unroll
        for (int s = 0; s < 9; ++s) b3f[s] = w3bp[s*64 + l];
        for (int tile = wave; tile < 16; tile += 4) {
            const int mb = tile * 32;
            int row = mb + (l & 31);
            int pr = (row < 484) ? row : 483;
            const int y = pr / 22, xx = pr % 22;
            v16i acc = {0,0,0,0,0,0,0,0,0,0,0,0,0,0,0,0};
            #pragma unroll
            for (int s = 0; s < 9; ++s) {
                const int ky = s / 3, kx = s - ky*3;
                uint m = h2b[(y + ky)*24 + (xx + kx)];
                uint part = m >> (16*half);
                v4i a;
                a[0] = expand4(part & 0xFu);
                a[1] = expand4((part >> 4) & 0xFu);
                a[2] = expand4((part >> 8) & 0xFu);
                a[3] = expand4((part >> 12) & 0xFu);
                acc = __builtin_amdgcn_mfma_i32_32x32x32_i8(a, b3f[s], acc, 0, 0, 0);
            }
            #pragma unroll
            for (int r = 0; r < 16; ++r) {
                unsigned long long mm = __ballot(acc[r] >= 0);
                int ra = mb + (r & 3) + 8*(r >> 2);
                if (l < 2) {
                    int addr = ra + 4*l;
                    if (addr < 484) {
                        uint val = (l == 0) ? (uint)mm : (uint)(mm >> 32);
                        h3[addr] = val;
                    }
                }
            }
        }
    }
    __syncthreads();

    // ---- avgpool + FC as binary dot (pairs packed in u32 halves) ----
    uint acc5[5] = {0u, 0u, 0u, 0u, 0u};
    for (int p = t; p < 484; p += 256) {
        uint h = h3[p];
        const uint* wp = wsu + WS_FC + p;
        #pragma unroll
        for (int o = 0; o < 5; ++o)
            acc5[o] += (uint)__popc(h ^ wp[(2*o)*484])
                     + ((uint)__popc(h ^ wp[(2*o+1)*484]) << 16);
    }
    #pragma unroll
    for (int o = 0; o < 5; ++o) {
        uint v = acc5[o];
        v += __shfl_down(v, 32); v += __shfl_down(v, 16);
        v += __shfl_down(v, 8);  v += __shfl_down(v, 4);
        v += __shfl_down(v, 2);  v += __shfl_down(v, 1);
        acc5[o] = v;
    }
    if (l == 0) {
        #pragma unroll
        for (int o = 0; o < 5; ++o) red[wave][o] = acc5[o];
    }
    __syncthreads();
    if (t < 10) {
        uint S = 0;
        #pragma unroll
        for (int j = 0; j < 4; ++j) {
            uint w = red[j][t >> 1];
            S += (t & 1) ? (w >> 16) : (w & 0xFFFFu);
        }
        lg[t] = 0.25f * (float)(15488 - 2*(int)S) + bfc[t];
    }
    __syncthreads();
    if (t < 10) {
        float m = lg[0];
        #pragma unroll
        for (int o = 1; o < 10; ++o) m = fmaxf(m, lg[o]);
        float se = 0.f;
        #pragma unroll
        for (int o = 0; o < 10; ++o) se += expf(lg[o] - m);
        out[(size_t)img*10 + t] = lg[t] - m - logf(se);
    }
}

extern "C" void kernel_launch(void* const* d_in, const int* in_sizes, int n_in,
                              void* d_out, int out_size, void* d_ws, size_t ws_size,
                              hipStream_t stream)
{
    const float* x   = (const float*)d_in[0];
    const float* w1  = (const float*)d_in[1];
    const float* w2  = (const float*)d_in[2];
    const float* w3  = (const float*)d_in[3];
    const float* wfc = (const float*)d_in[4];
    const float* bfc = (const float*)d_in[5];
    float* out = (float*)d_out;
    uint* wsu  = (uint*)d_ws;

    const int B = in_sizes[0] / 784;   // 8192

    hipLaunchKernelGGL(pack_kernel, dim3(23), dim3(256), 0, stream,
                       w1, w2, w3, wfc, wsu);
    hipLaunchKernelGGL(binet_kernel, dim3(B), dim3(256), 0, stream,
                       x, wsu, bfc, out);
}

// Round 5
// 293.496 us; speedup vs baseline: 5.9050x; 5.9050x over previous
//
#include <hip/hip_runtime.h>
#include <cstdint>

typedef unsigned uint;
typedef unsigned short u16;
typedef int v4i  __attribute__((ext_vector_type(4)));
typedef int v16i __attribute__((ext_vector_type(16)));

// d_ws word layout:
//   [0,144)       w1 signs as +-1.0f
//   [144,1424)    W2B: conv2 B-frags, frag f=s*64+l, 4 words each (16 i8)
//   [1424,3728)   W3B: conv3 B-frags, frag f=s*64+l, 4 words each
//   [3728,8568)   wfc packed+expanded to 22x22 grid (10*484 words)
static constexpr int WS_W2B = 144;
static constexpr int WS_W3B = 1424;
static constexpr int WS_FC  = 3728;

// LDS byte offsets (all phases disjoint, barriers between)
static constexpr int L_XS  = 0;      // float[784]   (conv1 in)
static constexpr int L_W1  = 3136;   // float[144]   (conv1 weights)
static constexpr int L_H1B = 3712;   // u16[676]     (conv1 out / conv2 in, bit ic)
static constexpr int L_H2B = 5064;   // uint[576]    (conv2 out / conv3 in, bit ic)
static constexpr int L_H3  = 7368;   // uint[484]    (conv3 out / FC in, bit ic)
static constexpr int L_RED = 9304;   // uint[4][5]
static constexpr int L_LG  = 9384;   // float[10]
static constexpr int L_TOT = 9424;

__global__ __launch_bounds__(256) void pack_kernel(
    const float* __restrict__ w1, const float* __restrict__ w2,
    const float* __restrict__ w3, const float* __restrict__ wfc,
    uint* __restrict__ wsu)
{
    int gid = blockIdx.x * 256 + threadIdx.x;
    if (gid < 144) {
        ((float*)wsu)[gid] = (w1[gid] >= 0.f) ? 1.f : -1.f;
    } else if (gid < 464) {
        // conv2 B fragment: oc = l&31, tap = 2s + (l>>5), ic = e (K = tap*16+ic)
        int f = gid - 144, s = f >> 6, l = f & 63;
        int oc = l & 31, tap = s * 2 + (l >> 5);
        uint w[4] = {0u, 0u, 0u, 0u};
        if (tap < 9) {
            for (int e = 0; e < 16; ++e) {
                uint b = (w2[(oc * 16 + e) * 9 + tap] >= 0.f) ? 0x01u : 0xFFu;
                w[e >> 2] |= b << (8 * (e & 3));
            }
        }
        for (int j = 0; j < 4; ++j) wsu[WS_W2B + f * 4 + j] = w[j];
    } else if (gid < 1040) {
        // conv3 B fragment: oc = l&31, tap = s, ic = (l>>5)*16 + e (K = tap*32+ic)
        int f = gid - 464, s = f >> 6, l = f & 63;
        int oc = l & 31, icb = (l >> 5) * 16;
        uint w[4] = {0u, 0u, 0u, 0u};
        for (int e = 0; e < 16; ++e) {
            uint b = (w3[(oc * 32 + icb + e) * 9 + s] >= 0.f) ? 0x01u : 0xFFu;
            w[e >> 2] |= b << (8 * (e & 3));
        }
        for (int j = 0; j < 4; ++j) wsu[WS_W3B + f * 4 + j] = w[j];
    } else if (gid < 5880) {
        int f = gid - 1040, o = f / 484, p = f % 484;
        int Y = p / 22, X = p % 22;
        const float* base = wfc + o * 3872 + (Y >> 1) * 11 + (X >> 1);
        uint bits = 0;
        for (int c = 0; c < 32; ++c)
            bits |= (base[c * 121] >= 0.f ? 1u : 0u) << c;
        wsu[WS_FC + f] = bits;
    }
}

// 4 sign bits -> 4 i8 bytes (+1 / -1)
__device__ __forceinline__ int expand4(uint t) {
    return (int)~(((t * 0x00204081u) & 0x01010101u) * 0xFEu);
}

__global__ __launch_bounds__(256) void binet_kernel(
    const float* __restrict__ x, const uint* __restrict__ wsu,
    const float* __restrict__ bfc, float* __restrict__ out)
{
    __shared__ __align__(16) unsigned char lds[L_TOT];
    const int t = threadIdx.x;
    const int img = blockIdx.x;
    const int l = t & 63, wave = t >> 6, half = l >> 5;

    float* xs  = (float*)(lds + L_XS);
    float* w1f = (float*)(lds + L_W1);
    u16*   h1b = (u16*)(lds + L_H1B);
    uint*  h2b = (uint*)(lds + L_H2B);
    uint*  h3  = (uint*)(lds + L_H3);
    uint (*red)[5] = (uint(*)[5])(lds + L_RED);
    float* lg  = (float*)(lds + L_LG);

    // ---- load image + conv1 weights into LDS ----
    {
        const float* xin = x + (size_t)img * 784;
        for (int i = t; i < 784; i += 256) xs[i] = xin[i];
        if (t < 144) w1f[t] = ((const float*)wsu)[t];
    }
    __syncthreads();

    // ---- conv1: fp32 fast path, rare fp64 fallback; pack 16 sign bits ----
    {
        const int p0 = t, p1 = t + 256, p2 = t + 512;
        const bool has2 = (p2 < 676);
        const int y0 = p0 / 26, x0 = p0 % 26;
        const int y1 = p1 / 26, x1 = p1 % 26;
        const int y2 = has2 ? p2 / 26 : 0, x2 = has2 ? p2 % 26 : 0;
        float xv0[9], xv1[9], xv2[9];
        #pragma unroll
        for (int ky = 0; ky < 3; ++ky)
            #pragma unroll
            for (int kx = 0; kx < 3; ++kx) {
                xv0[ky*3+kx] = xs[(y0+ky)*28 + x0 + kx];
                xv1[ky*3+kx] = xs[(y1+ky)*28 + x1 + kx];
                xv2[ky*3+kx] = xs[(y2+ky)*28 + x2 + kx];
            }
        uint m0 = 0, m1 = 0, m2 = 0;
        for (int oc = 0; oc < 16; ++oc) {
            float s0 = 0.f, s1 = 0.f, s2 = 0.f;
            #pragma unroll
            for (int k = 0; k < 9; ++k) {
                float w = w1f[oc*9 + k];          // uniform -> LDS broadcast
                s0 = fmaf(xv0[k], w, s0);
                s1 = fmaf(xv1[k], w, s1);
                s2 = fmaf(xv2[k], w, s2);
            }
            bool b0 = (s0 >= 0.f), b1 = (s1 >= 0.f), b2 = (s2 >= 0.f);
            // fp32 worst-case accum error ~2.5e-5 << 1e-4: outside the band
            // the fp32 sign equals the exact (fp64) sign.
            if (__builtin_expect(fabsf(s0) < 1e-4f, 0)) {
                double sd = 0.0;
                for (int k = 0; k < 9; ++k) sd += (double)xv0[k] * (double)w1f[oc*9+k];
                b0 = (sd >= 0.0);
            }
            if (__builtin_expect(fabsf(s1) < 1e-4f, 0)) {
                double sd = 0.0;
                for (int k = 0; k < 9; ++k) sd += (double)xv1[k] * (double)w1f[oc*9+k];
                b1 = (sd >= 0.0);
            }
            if (__builtin_expect(fabsf(s2) < 1e-4f, 0)) {
                double sd = 0.0;
                for (int k = 0; k < 9; ++k) sd += (double)xv2[k] * (double)w1f[oc*9+k];
                b2 = (sd >= 0.0);
            }
            m0 |= (uint)b0 << oc;
            m1 |= (uint)b1 << oc;
            m2 |= (uint)b2 << oc;
        }
        h1b[p0] = (u16)m0;
        h1b[p1] = (u16)m1;
        if (has2) h1b[p2] = (u16)m2;
    }
    __syncthreads();

    // ---- conv2 via i8 MFMA: M=576 pos, N=32 oc, K=144 (pad 160) ----
    {
        const v4i* w2bp = (const v4i*)(wsu + WS_W2B);
        v4i b2f[5];
        #pragma unroll
        for (int s = 0; s < 5; ++s) b2f[s] = w2bp[s*64 + l];
        for (int tile = wave; tile < 18; tile += 4) {
            const int mb = tile * 32;
            const int row = mb + (l & 31);
            const int y = row / 24, xx = row % 24;
            v16i acc = {0,0,0,0,0,0,0,0,0,0,0,0,0,0,0,0};
            #pragma unroll
            for (int s = 0; s < 5; ++s) {
                int tap = s*2 + half; if (tap > 8) tap = 8;  // B zero-padded for tap 9
                int ky = tap / 3, kx = tap - ky*3;
                uint bits = (uint)h1b[(y + ky)*26 + (xx + kx)];
                v4i a;
                a[0] = expand4(bits & 0xFu);
                a[1] = expand4((bits >> 4) & 0xFu);
                a[2] = expand4((bits >> 8) & 0xFu);
                a[3] = expand4((bits >> 12) & 0xFu);
                acc = __builtin_amdgcn_mfma_i32_32x32x32_i8(a, b2f[s], acc, 0, 0, 0);
            }
            #pragma unroll
            for (int r = 0; r < 16; ++r) {
                unsigned long long mm = __ballot(acc[r] >= 0);  // bit l = sign of oc l
                int ra = mb + (r & 3) + 8*(r >> 2);
                if (l < 2) {
                    uint val = (l == 0) ? (uint)mm : (uint)(mm >> 32);
                    h2b[ra + 4*l] = val;
                }
            }
        }
    }
    __syncthreads();

    // ---- conv3 via i8 MFMA: M=484 (pad 512), N=32 oc, K=288 ----
    {
        const v4i* w3bp = (const v4i*)(wsu + WS_W3B);
        v4i b3f[9];
        #pragma unroll
        for (int s = 0; s < 9; ++s) b3f[s] = w3bp[s*64 + l];
        for (int tile = wave; tile < 16; tile += 4) {
            const int mb = tile * 32;
            int row = mb + (l & 31);
            int pr = (row < 484) ? row : 483;
            const int y = pr / 22, xx = pr % 22;
            v16i acc = {0,0,0,0,0,0,0,0,0,0,0,0,0,0,0,0};
            #pragma unroll
            for (int s = 0; s < 9; ++s) {
                const int ky = s / 3, kx = s - ky*3;
                uint m = h2b[(y + ky)*24 + (xx + kx)];
                uint part = m >> (16*half);
                v4i a;
                a[0] = expand4(part & 0xFu);
                a[1] = expand4((part >> 4) & 0xFu);
                a[2] = expand4((part >> 8) & 0xFu);
                a[3] = expand4((part >> 12) & 0xFu);
                acc = __builtin_amdgcn_mfma_i32_32x32x32_i8(a, b3f[s], acc, 0, 0, 0);
            }
            #pragma unroll
            for (int r = 0; r < 16; ++r) {
                unsigned long long mm = __ballot(acc[r] >= 0);
                int ra = mb + (r & 3) + 8*(r >> 2);
                if (l < 2) {
                    int addr = ra + 4*l;
                    if (addr < 484) {
                        uint val = (l == 0) ? (uint)mm : (uint)(mm >> 32);
                        h3[addr] = val;
                    }
                }
            }
        }
    }
    __syncthreads();

    // ---- avgpool + FC as binary dot (pairs packed in u32 halves) ----
    uint acc5[5] = {0u, 0u, 0u, 0u, 0u};
    for (int p = t; p < 484; p += 256) {
        uint h = h3[p];
        const uint* wp = wsu + WS_FC + p;
        #pragma unroll
        for (int o = 0; o < 5; ++o)
            acc5[o] += (uint)__popc(h ^ wp[(2*o)*484])
                     + ((uint)__popc(h ^ wp[(2*o+1)*484]) << 16);
    }
    #pragma unroll
    for (int o = 0; o < 5; ++o) {
        uint v = acc5[o];
        v += __shfl_down(v, 32); v += __shfl_down(v, 16);
        v += __shfl_down(v, 8);  v += __shfl_down(v, 4);
        v += __shfl_down(v, 2);  v += __shfl_down(v, 1);
        acc5[o] = v;
    }
    if (l == 0) {
        #pragma unroll
        for (int o = 0; o < 5; ++o) red[wave][o] = acc5[o];
    }
    __syncthreads();
    if (t < 10) {
        uint S = 0;
        #pragma unroll
        for (int j = 0; j < 4; ++j) {
            uint w = red[j][t >> 1];
            S += (t & 1) ? (w >> 16) : (w & 0xFFFFu);
        }
        lg[t] = 0.25f * (float)(15488 - 2*(int)S) + bfc[t];
    }
    __syncthreads();
    if (t < 10) {
        float m = lg[0];
        #pragma unroll
        for (int o = 1; o < 10; ++o) m = fmaxf(m, lg[o]);
        float se = 0.f;
        #pragma unroll
        for (int o = 0; o < 10; ++o) se += expf(lg[o] - m);
        out[(size_t)img*10 + t] = lg[t] - m - logf(se);
    }
}

extern "C" void kernel_launch(void* const* d_in, const int* in_sizes, int n_in,
                              void* d_out, int out_size, void* d_ws, size_t ws_size,
                              hipStream_t stream)
{
    const float* x   = (const float*)d_in[0];
    const float* w1  = (const float*)d_in[1];
    const float* w2  = (const float*)d_in[2];
    const float* w3  = (const float*)d_in[3];
    const float* wfc = (const float*)d_in[4];
    const float* bfc = (const float*)d_in[5];
    float* out = (float*)d_out;
    uint* wsu  = (uint*)d_ws;

    const int B = in_sizes[0] / 784;   // 8192

    hipLaunchKernelGGL(pack_kernel, dim3(23), dim3(256), 0, stream,
                       w1, w2, w3, wfc, wsu);
    hipLaunchKernelGGL(binet_kernel, dim3(B), dim3(256), 0, stream,
                       x, wsu, bfc, out);
}

// Round 6
// 258.259 us; speedup vs baseline: 6.7107x; 1.1364x over previous
//
#include <hip/hip_runtime.h>
#include <cstdint>

typedef unsigned uint;
typedef unsigned short u16;
typedef int v4i  __attribute__((ext_vector_type(4)));
typedef int v16i __attribute__((ext_vector_type(16)));

// d_ws word layout:
//   [0,144)       w1 signs as +-1.0f
//   [144,1424)    W2B: conv2 B-frags, frag f=s*64+l, 4 words each (16 i8)
//   [1424,3728)   W3B: conv3 B-frags, frag f=s*64+l, 4 words each
//   [3728,8568)   wfc packed+expanded to 22x22 grid (10*484 words)
static constexpr int WS_W2B = 144;
static constexpr int WS_W3B = 1424;
static constexpr int WS_FC  = 3728;

// LDS byte offsets. Phase lifetimes:
//   conv1:  reads xs,w1f            writes h1 (i8)
//   conv2:  reads h1                writes h2b (words, ballot)
//   expand: reads h2b               writes h2i (overlays xs/w1f/h1 - dead)
//   conv3:  reads h2i               writes h3 (words)
//   fc:     reads h3                writes red/lg
static constexpr int L_H2I = 0;      // i8 [2][576][16] = 18432   (expand out)
static constexpr int L_XS  = 0;      // float[784] = 3136         (conv1 in)
static constexpr int L_W1  = 3136;   // float[144] = 576
static constexpr int L_H1  = 3712;   // i8 [676][16] = 10816      (ends 14528)
static constexpr int L_H2B = 18432;  // uint[576] = 2304          (ends 20736)
static constexpr int L_H3  = 20736;  // uint[484] = 1936          (ends 22672)
static constexpr int L_RED = 22672;  // uint[4][5] = 80
static constexpr int L_LG  = 22752;  // float[10]  = 40
static constexpr int L_TOT = 22792;

__global__ __launch_bounds__(256) void pack_kernel(
    const float* __restrict__ w1, const float* __restrict__ w2,
    const float* __restrict__ w3, const float* __restrict__ wfc,
    uint* __restrict__ wsu)
{
    int gid = blockIdx.x * 256 + threadIdx.x;
    if (gid < 144) {
        ((float*)wsu)[gid] = (w1[gid] >= 0.f) ? 1.f : -1.f;
    } else if (gid < 464) {
        // conv2 B fragment: oc = l&31, tap = 2s + (l>>5), ic = e (K = tap*16+ic)
        int f = gid - 144, s = f >> 6, l = f & 63;
        int oc = l & 31, tap = s * 2 + (l >> 5);
        uint w[4] = {0u, 0u, 0u, 0u};
        if (tap < 9) {
            for (int e = 0; e < 16; ++e) {
                uint b = (w2[(oc * 16 + e) * 9 + tap] >= 0.f) ? 0x01u : 0xFFu;
                w[e >> 2] |= b << (8 * (e & 3));
            }
        }
        for (int j = 0; j < 4; ++j) wsu[WS_W2B + f * 4 + j] = w[j];
    } else if (gid < 1040) {
        // conv3 B fragment: oc = l&31, tap = s, ic = (l>>5)*16 + e (K = tap*32+ic)
        int f = gid - 464, s = f >> 6, l = f & 63;
        int oc = l & 31, icb = (l >> 5) * 16;
        uint w[4] = {0u, 0u, 0u, 0u};
        for (int e = 0; e < 16; ++e) {
            uint b = (w3[(oc * 32 + icb + e) * 9 + s] >= 0.f) ? 0x01u : 0xFFu;
            w[e >> 2] |= b << (8 * (e & 3));
        }
        for (int j = 0; j < 4; ++j) wsu[WS_W3B + f * 4 + j] = w[j];
    } else if (gid < 5880) {
        int f = gid - 1040, o = f / 484, p = f % 484;
        int Y = p / 22, X = p % 22;
        const float* base = wfc + o * 3872 + (Y >> 1) * 11 + (X >> 1);
        uint bits = 0;
        for (int c = 0; c < 32; ++c)
            bits |= (base[c * 121] >= 0.f ? 1u : 0u) << c;
        wsu[WS_FC + f] = bits;
    }
}

// 4 sign bits -> 4 i8 bytes (bit=1 -> +1, bit=0 -> -1)
__device__ __forceinline__ int expand4(uint t) {
    return (int)~(((t * 0x00204081u) & 0x01010101u) * 0xFEu);
}
__device__ __forceinline__ v4i expand16(uint bits) {
    v4i r;
    r[0] = expand4(bits & 0xFu);
    r[1] = expand4((bits >> 4) & 0xFu);
    r[2] = expand4((bits >> 8) & 0xFu);
    r[3] = expand4((bits >> 12) & 0xFu);
    return r;
}

__global__ __launch_bounds__(256) void binet_kernel(
    const float* __restrict__ x, const uint* __restrict__ wsu,
    const float* __restrict__ bfc, float* __restrict__ out)
{
    __shared__ __align__(16) unsigned char lds[L_TOT];
    const int t = threadIdx.x;
    const int img = blockIdx.x;
    const int l = t & 63, wave = t >> 6, half = l >> 5;

    float* xs  = (float*)(lds + L_XS);
    float* w1f = (float*)(lds + L_W1);
    signed char* h1  = (signed char*)(lds + L_H1);
    uint*  h2b = (uint*)(lds + L_H2B);
    signed char* h2i = (signed char*)(lds + L_H2I);
    uint*  h3  = (uint*)(lds + L_H3);
    uint (*red)[5] = (uint(*)[5])(lds + L_RED);
    float* lg  = (float*)(lds + L_LG);

    // ---- load image + conv1 weights into LDS ----
    {
        const float* xin = x + (size_t)img * 784;
        for (int i = t; i < 784; i += 256) xs[i] = xin[i];
        if (t < 144) w1f[t] = ((const float*)wsu)[t];
    }
    __syncthreads();

    // ---- conv1: fp32 fast path, rare fp64 fallback; write i8 +-1 (b128) ----
    {
        const int p0 = t, p1 = t + 256, p2 = t + 512;
        const bool has2 = (p2 < 676);
        const int y0 = p0 / 26, x0 = p0 % 26;
        const int y1 = p1 / 26, x1 = p1 % 26;
        const int y2 = has2 ? p2 / 26 : 0, x2 = has2 ? p2 % 26 : 0;
        float xv0[9], xv1[9], xv2[9];
        #pragma unroll
        for (int ky = 0; ky < 3; ++ky)
            #pragma unroll
            for (int kx = 0; kx < 3; ++kx) {
                xv0[ky*3+kx] = xs[(y0+ky)*28 + x0 + kx];
                xv1[ky*3+kx] = xs[(y1+ky)*28 + x1 + kx];
                xv2[ky*3+kx] = xs[(y2+ky)*28 + x2 + kx];
            }
        uint m0 = 0, m1 = 0, m2 = 0;
        for (int oc = 0; oc < 16; ++oc) {
            float s0 = 0.f, s1 = 0.f, s2 = 0.f;
            #pragma unroll
            for (int k = 0; k < 9; ++k) {
                float w = w1f[oc*9 + k];          // uniform -> broadcast
                s0 = fmaf(xv0[k], w, s0);
                s1 = fmaf(xv1[k], w, s1);
                s2 = fmaf(xv2[k], w, s2);
            }
            bool b0 = (s0 >= 0.f), b1 = (s1 >= 0.f), b2 = (s2 >= 0.f);
            // fp32 accum error bound ~2.5e-5 << 1e-4: outside the band the
            // fp32 sign equals the exact (fp64) sign.
            if (__builtin_expect(fabsf(s0) < 1e-4f, 0)) {
                double sd = 0.0;
                for (int k = 0; k < 9; ++k) sd += (double)xv0[k] * (double)w1f[oc*9+k];
                b0 = (sd >= 0.0);
            }
            if (__builtin_expect(fabsf(s1) < 1e-4f, 0)) {
                double sd = 0.0;
                for (int k = 0; k < 9; ++k) sd += (double)xv1[k] * (double)w1f[oc*9+k];
                b1 = (sd >= 0.0);
            }
            if (__builtin_expect(fabsf(s2) < 1e-4f, 0)) {
                double sd = 0.0;
                for (int k = 0; k < 9; ++k) sd += (double)xv2[k] * (double)w1f[oc*9+k];
                b2 = (sd >= 0.0);
            }
            m0 |= (uint)b0 << oc;
            m1 |= (uint)b1 << oc;
            m2 |= (uint)b2 << oc;
        }
        *(v4i*)(h1 + p0*16) = expand16(m0);
        *(v4i*)(h1 + p1*16) = expand16(m1);
        if (has2) *(v4i*)(h1 + p2*16) = expand16(m2);
    }
    __syncthreads();

    // ---- conv2 via i8 MFMA: M=576 pos, N=32 oc, K=144 (pad 160) ----
    // A: direct b128 from h1 (1 LDS op per MFMA). Epilogue: ballot -> words.
    {
        const v4i* w2bp = (const v4i*)(wsu + WS_W2B);
        v4i b2f[5];
        #pragma unroll
        for (int s = 0; s < 5; ++s) b2f[s] = w2bp[s*64 + l];
        for (int tile = wave; tile < 18; tile += 4) {
            const int mb = tile * 32;
            const int row = mb + (l & 31);
            const int y = row / 24, xx = row % 24;
            v16i acc = {0,0,0,0,0,0,0,0,0,0,0,0,0,0,0,0};
            #pragma unroll
            for (int s = 0; s < 5; ++s) {
                int tap = s*2 + half; if (tap > 8) tap = 8;  // B zeroed for tap 9
                int ky = tap / 3, kx = tap - ky*3;
                v4i a = *(const v4i*)(h1 + ((y + ky)*26 + (xx + kx))*16);
                acc = __builtin_amdgcn_mfma_i32_32x32x32_i8(a, b2f[s], acc, 0, 0, 0);
            }
            #pragma unroll
            for (int r = 0; r < 16; ++r) {
                unsigned long long mm = __ballot(acc[r] >= 0);  // bit l = oc l sign
                int ra = mb + (r & 3) + 8*(r >> 2);
                if (l < 2) {
                    uint val = (l == 0) ? (uint)mm : (uint)(mm >> 32);
                    h2b[ra + 4*l] = val;
                }
            }
        }
    }
    __syncthreads();

    // ---- expand h2b words -> h2i [2][576][16] i8 (once per position) ----
    for (int p = t; p < 576; p += 256) {
        uint w = h2b[p];
        *(v4i*)(h2i + p*16)        = expand16(w & 0xFFFFu);
        *(v4i*)(h2i + 9216 + p*16) = expand16(w >> 16);
    }
    __syncthreads();

    // ---- conv3 via i8 MFMA: M=484 (pad 512), N=32 oc, K=288 ----
    // A: b128 from half-split h2i -> 16B-consecutive per half-wave.
    {
        const v4i* w3bp = (const v4i*)(wsu + WS_W3B);
        v4i b3f[9];
        #pragma unroll
        for (int s = 0; s < 9; ++s) b3f[s] = w3bp[s*64 + l];
        const signed char* h2h = h2i + half*9216;
        for (int tile = wave; tile < 16; tile += 4) {
            const int mb = tile * 32;
            int row = mb + (l & 31);
            int pr = (row < 484) ? row : 483;
            const int y = pr / 22, xx = pr % 22;
            v16i acc = {0,0,0,0,0,0,0,0,0,0,0,0,0,0,0,0};
            #pragma unroll
            for (int s = 0; s < 9; ++s) {
                const int ky = s / 3, kx = s - ky*3;
                v4i a = *(const v4i*)(h2h + ((y + ky)*24 + (xx + kx))*16);
                acc = __builtin_amdgcn_mfma_i32_32x32x32_i8(a, b3f[s], acc, 0, 0, 0);
            }
            #pragma unroll
            for (int r = 0; r < 16; ++r) {
                unsigned long long mm = __ballot(acc[r] >= 0);
                int ra = mb + (r & 3) + 8*(r >> 2);
                if (l < 2) {
                    int addr = ra + 4*l;
                    if (addr < 484) {
                        uint val = (l == 0) ? (uint)mm : (uint)(mm >> 32);
                        h3[addr] = val;
                    }
                }
            }
        }
    }
    __syncthreads();

    // ---- avgpool + FC as binary dot (pairs packed in u32 halves) ----
    uint acc5[5] = {0u, 0u, 0u, 0u, 0u};
    for (int p = t; p < 484; p += 256) {
        uint h = h3[p];
        const uint* wp = wsu + WS_FC + p;
        #pragma unroll
        for (int o = 0; o < 5; ++o)
            acc5[o] += (uint)__popc(h ^ wp[(2*o)*484])
                     + ((uint)__popc(h ^ wp[(2*o+1)*484]) << 16);
    }
    #pragma unroll
    for (int o = 0; o < 5; ++o) {
        uint v = acc5[o];
        v += __shfl_down(v, 32); v += __shfl_down(v, 16);
        v += __shfl_down(v, 8);  v += __shfl_down(v, 4);
        v += __shfl_down(v, 2);  v += __shfl_down(v, 1);
        acc5[o] = v;
    }
    if (l == 0) {
        #pragma unroll
        for (int o = 0; o < 5; ++o) red[wave][o] = acc5[o];
    }
    __syncthreads();
    if (t < 10) {
        uint S = 0;
        #pragma unroll
        for (int j = 0; j < 4; ++j) {
            uint w = red[j][t >> 1];
            S += (t & 1) ? (w >> 16) : (w & 0xFFFFu);
        }
        lg[t] = 0.25f * (float)(15488 - 2*(int)S) + bfc[t];
    }
    __syncthreads();
    if (t < 10) {
        float m = lg[0];
        #pragma unroll
        for (int o = 1; o < 10; ++o) m = fmaxf(m, lg[o]);
        float se = 0.f;
        #pragma unroll
        for (int o = 0; o < 10; ++o) se += expf(lg[o] - m);
        out[(size_t)img*10 + t] = lg[t] - m - logf(se);
    }
}

extern "C" void kernel_launch(void* const* d_in, const int* in_sizes, int n_in,
                              void* d_out, int out_size, void* d_ws, size_t ws_size,
                              hipStream_t stream)
{
    const float* x   = (const float*)d_in[0];
    const float* w1  = (const float*)d_in[1];
    const float* w2  = (const float*)d_in[2];
    const float* w3  = (const float*)d_in[3];
    const float* wfc = (const float*)d_in[4];
    const float* bfc = (const float*)d_in[5];
    float* out = (float*)d_out;
    uint* wsu  = (uint*)d_ws;

    const int B = in_sizes[0] / 784;   // 8192

    hipLaunchKernelGGL(pack_kernel, dim3(23), dim3(256), 0, stream,
                       w1, w2, w3, wfc, wsu);
    hipLaunchKernelGGL(binet_kernel, dim3(B), dim3(256), 0, stream,
                       x, wsu, bfc, out);
}